// Round 6
// baseline (262.657 us; speedup 1.0000x reference)
//
#include <hip/hip_runtime.h>
#include <math.h>

namespace {
constexpr int Bn = 2, CF = 64;
constexpr int H = 256, W = 256, HW = H * W;
constexpr int IH = 512, IW = 512;

// ws layout in floats
constexpr int OFF_MT   = 0;                        // Mt[y][x], 256*256
constexpr int OFF_GXX  = OFF_MT + 256 * 256;       // [3][256] j-major
constexpr int OFF_GYY  = OFF_GXX + 3 * 256;        // [3][256]
constexpr int OFF_G    = OFF_GYY + 3 * 256;        // 3x3 = w_img^T w_img (pad 16)
constexpr int OFF_RIMG = OFF_G + 16;               // [b][c3][HW]
constexpr int OFF_S    = OFF_RIMG + Bn * 3 * HW;   // sigs: Bn*HW = sigmoid(smap)

// fused prep partition
constexpr int GRAM_BLOCKS = 256;
constexpr int RIMG_BLOCKS = Bn * 3 * (HW / 256);   // 1536
constexpr int SIGS_BLOCKS = Bn * (HW / 256);       // 512 (float4, 4 px/thread)
constexpr int PREP_BLOCKS = GRAM_BLOCKS + RIMG_BLOCKS + SIGS_BLOCKS; // 2304

constexpr float DEXP = -0.2878231366242557f;       // -ln(1e4)/32
}

// ---------------------------------------------------------------------------
// prep (fused, 2304 blocks, 2 launches total for the whole op):
//   [0,256)     gram via quadratic form: Mt[t][a] = u_a^T K u_t with
//               K = Wx^T Wy (32x32, coop-computed in LDS). No PX/PY buffers,
//               no pxy kernel, no cross-block dependency. Block 0 adds
//               GXX/GYY via the symmetric grams KX=Wx^T Wx, KY=Wy^T Wy
//               (u_a^T KX u_{a+d} = u_{a+d}^T KX u_a), plus G = w_img^T w_img.
//   [256,1792)  rimg: antialiased 2x bilinear downsample of img.
//   [1792,2304) sigs: sigmoid(dot_c(inp,w_comp)), float4 loads.
// All branches are block-uniform (syncthreads legal within each branch).
// ---------------------------------------------------------------------------
__device__ __forceinline__ void resize_taps(int p, int n, float w[4], int idx[4])
{
#pragma unroll
  for (int r = 0; r < 4; r++) {
    int q = 2 * p - 1 + r;
    idx[r] = min(max(q, 0), 2 * n - 1);
  }
  if (p == 0)          { w[0] = 0.f;        w[1] = 3.f / 7.f; w[2] = 3.f / 7.f; w[3] = 1.f / 7.f; }
  else if (p == n - 1) { w[0] = 1.f / 7.f;  w[1] = 3.f / 7.f; w[2] = 3.f / 7.f; w[3] = 0.f; }
  else                 { w[0] = 0.125f;     w[1] = 0.375f;    w[2] = 0.375f;    w[3] = 0.125f; }
}

__global__ __launch_bounds__(256) void prep_kernel(
    const float* __restrict__ img, const float* __restrict__ inp,
    const float* __restrict__ w_comp, const float* __restrict__ w_img,
    const float* __restrict__ w_pos,
    float* __restrict__ rimg, float* __restrict__ sigs,
    float* __restrict__ Mt, float* __restrict__ GXX, float* __restrict__ GYY,
    float* __restrict__ G)
{
  // union LDS: gram uses wp|K|KX|KY|wv (5152 floats); sigs uses first 1024
  // as float4 red[256]. Different blocks -> no aliasing hazard.
  __shared__ __align__(16) float smem[5152];
  const int gid = blockIdx.x;

  if (gid < GRAM_BLOCKS) {
    // ---- gram part ----
    float* wp  = smem;            // [32][64] w_pos staged
    float* Ks  = smem + 2048;     // [32][32] Wx^T Wy
    float* KXs = smem + 3072;     // [32][32] Wx^T Wx (block 0 only)
    float* KYs = smem + 4096;     // [32][32] Wy^T Wy (block 0 only)
    float* wv  = smem + 5120;     // [32] K . u_t
    const int a = threadIdx.x;
    const int t = gid;

    // stage w_pos (2048 floats, coalesced)
#pragma unroll
    for (int i = 0; i < 8; i++) wp[i * 256 + a] = w_pos[i * 256 + a];
    __syncthreads();

    // K coop: thread -> row Ki, cols Kj0..Kj0+3
    const int Ki = a >> 3;
    const int Kj0 = (a & 7) * 4;
    {
      float k0 = 0.f, k1 = 0.f, k2 = 0.f, k3 = 0.f;
#pragma unroll
      for (int o = 0; o < 32; o++) {
        const float xe = wp[o * 64 + Ki];
        const float* yo = wp + o * 64 + 32;
        k0 += xe * yo[Kj0 + 0];
        k1 += xe * yo[Kj0 + 1];
        k2 += xe * yo[Kj0 + 2];
        k3 += xe * yo[Kj0 + 3];
      }
      Ks[Ki * 32 + Kj0 + 0] = k0;
      Ks[Ki * 32 + Kj0 + 1] = k1;
      Ks[Ki * 32 + Kj0 + 2] = k2;
      Ks[Ki * 32 + Kj0 + 3] = k3;
    }
    if (t == 0) {
      float x0 = 0.f, x1 = 0.f, x2 = 0.f, x3 = 0.f;
      float y0 = 0.f, y1 = 0.f, y2 = 0.f, y3 = 0.f;
#pragma unroll
      for (int o = 0; o < 32; o++) {
        const float xe = wp[o * 64 + Ki];
        const float ye = wp[o * 64 + 32 + Ki];
        const float* xo = wp + o * 64;
        const float* yo = wp + o * 64 + 32;
        x0 += xe * xo[Kj0 + 0]; x1 += xe * xo[Kj0 + 1];
        x2 += xe * xo[Kj0 + 2]; x3 += xe * xo[Kj0 + 3];
        y0 += ye * yo[Kj0 + 0]; y1 += ye * yo[Kj0 + 1];
        y2 += ye * yo[Kj0 + 2]; y3 += ye * yo[Kj0 + 3];
      }
      KXs[Ki * 32 + Kj0 + 0] = x0; KXs[Ki * 32 + Kj0 + 1] = x1;
      KXs[Ki * 32 + Kj0 + 2] = x2; KXs[Ki * 32 + Kj0 + 3] = x3;
      KYs[Ki * 32 + Kj0 + 0] = y0; KYs[Ki * 32 + Kj0 + 1] = y1;
      KYs[Ki * 32 + Kj0 + 2] = y2; KYs[Ki * 32 + Kj0 + 3] = y3;
    }
    __syncthreads();

    // w = K . u_t (uniform), by threads 0..31
    if (a < 32) {
      float acc = 0.f;
#pragma unroll
      for (int i = 0; i < 16; i++) {
        const float d = expf((float)(2 * i) * DEXP);
        const float ang = (float)t * d;
        acc += Ks[a * 32 + 2 * i] * sinf(ang) + Ks[a * 32 + 2 * i + 1] * cosf(ang);
      }
      wv[a] = acc;
    }
    __syncthreads();

    // u_a and Mt[t][a] = u_a . wv
    float sa[16], ca[16];
#pragma unroll
    for (int i = 0; i < 16; i++) {
      const float d = expf((float)(2 * i) * DEXP);
      const float ang = (float)a * d;
      sa[i] = sinf(ang);
      ca[i] = cosf(ang);
    }
    float m = 0.f;
#pragma unroll
    for (int i = 0; i < 16; i++) m += wv[2 * i] * sa[i] + wv[2 * i + 1] * ca[i];
    Mt[t * 256 + a] = m;

    if (t == 0) {
      // GXX[j][a] = u_a^T KX u_{a+2(j-1)} = sum_e u_nb[e] * (KX u_a)[e]
      // (KX symmetric). Stream e to keep VGPR low; u_nb computed inline.
      float gx0 = 0.f, gx1 = 0.f, gx2 = 0.f;
      float gy0 = 0.f, gy1 = 0.f, gy2 = 0.f;
#pragma unroll
      for (int i = 0; i < 16; i++) {   // e = 2i (sin) and 2i+1 (cos)
        const float d = expf((float)(2 * i) * DEXP);
        // zx[e] = sum_f KX[e][f] u_a[f]
        float zxs = 0.f, zxc = 0.f, zys = 0.f, zyc = 0.f;
#pragma unroll
        for (int f = 0; f < 16; f++) {
          zxs += KXs[(2 * i) * 32 + 2 * f] * sa[f] + KXs[(2 * i) * 32 + 2 * f + 1] * ca[f];
          zxc += KXs[(2 * i + 1) * 32 + 2 * f] * sa[f] + KXs[(2 * i + 1) * 32 + 2 * f + 1] * ca[f];
          zys += KYs[(2 * i) * 32 + 2 * f] * sa[f] + KYs[(2 * i) * 32 + 2 * f + 1] * ca[f];
          zyc += KYs[(2 * i + 1) * 32 + 2 * f] * sa[f] + KYs[(2 * i + 1) * 32 + 2 * f + 1] * ca[f];
        }
        const float am = (float)(a - 2) * d, ap = (float)(a + 2) * d;
        const float sm = sinf(am), cm = cosf(am);
        const float sp = sinf(ap), cp = cosf(ap);
        gx0 += sm * zxs + cm * zxc;  gy0 += sm * zys + cm * zyc;
        gx1 += sa[i] * zxs + ca[i] * zxc;  gy1 += sa[i] * zys + ca[i] * zyc;
        gx2 += sp * zxs + cp * zxc;  gy2 += sp * zys + cp * zyc;
      }
      const bool vm = (a - 2) >= 0, vp = (a + 2) < 256;
      GXX[0 * 256 + a] = vm ? gx0 : 0.f;
      GXX[1 * 256 + a] = gx1;
      GXX[2 * 256 + a] = vp ? gx2 : 0.f;
      GYY[0 * 256 + a] = vm ? gy0 : 0.f;
      GYY[1 * 256 + a] = gy1;
      GYY[2 * 256 + a] = vp ? gy2 : 0.f;
      if (a < 9) {
        const int i = a / 3, j = a % 3;
        float g = 0.f;
#pragma unroll
        for (int o = 0; o < 32; o++) g += w_img[o * 3 + i] * w_img[o * 3 + j];
        G[a] = g;
      }
    }
  } else if (gid < GRAM_BLOCKS + RIMG_BLOCKS) {
    // ---- rimg part ----
    const int rid = gid - GRAM_BLOCKS;
    const int b = rid / 768;
    const int rem = rid % 768;
    const int c = rem / 256;
    const int p = (rem % 256) * 256 + threadIdx.x;
    const int x = p & (W - 1);
    const int y = p >> 8;

    float wy[4], wx[4];
    int ry[4], rx[4];
    resize_taps(y, H, wy, ry);
    resize_taps(x, W, wx, rx);

    const float* ip = img + ((size_t)(b * 3 + c) * IH) * IW;
    float acc = 0.f;
#pragma unroll
    for (int r = 0; r < 4; r++) {
      const float* rowp = ip + ry[r] * IW;
      float rs = wx[0] * rowp[rx[0]] + wx[1] * rowp[rx[1]] +
                 wx[2] * rowp[rx[2]] + wx[3] * rowp[rx[3]];
      acc += wy[r] * rs;
    }
    rimg[((size_t)(b * 3 + c)) * HW + p] = acc;
  } else {
    // ---- sigs part: float4, 4 px/thread, LDS float4 reduce ----
    float4* red4 = reinterpret_cast<float4*>(smem);
    const int sid = gid - (GRAM_BLOCKS + RIMG_BLOCKS);
    const int b = sid / (HW / 256);
    const int pblk = sid % (HW / 256);
    const int lane = threadIdx.x & 63;
    const int cg = threadIdx.x >> 6;         // 0..3
    const int p0 = pblk * 256 + lane * 4;

    const float* ib = inp + (size_t)b * CF * HW + (size_t)cg * 16 * HW + p0;
    float4 acc = {0.f, 0.f, 0.f, 0.f};
#pragma unroll
    for (int c = 0; c < 16; c++) {
      const float4 v = *reinterpret_cast<const float4*>(ib + (size_t)c * HW);
      const float wc = w_comp[cg * 16 + c];
      acc.x += v.x * wc; acc.y += v.y * wc;
      acc.z += v.z * wc; acc.w += v.w * wc;
    }
    red4[threadIdx.x] = acc;
    __syncthreads();
    if (threadIdx.x < 64) {
      const float4 a = red4[threadIdx.x];
      const float4 b1 = red4[threadIdx.x + 64];
      const float4 c1 = red4[threadIdx.x + 128];
      const float4 d = red4[threadIdx.x + 192];
      float4 s;
      s.x = (a.x + b1.x) + (c1.x + d.x);
      s.y = (a.y + b1.y) + (c1.y + d.y);
      s.z = (a.z + b1.z) + (c1.z + d.z);
      s.w = (a.w + b1.w) + (c1.w + d.w);
      s.x = 1.f / (1.f + expf(-s.x));
      s.y = 1.f / (1.f + expf(-s.y));
      s.z = 1.f / (1.f + expf(-s.z));
      s.w = 1.f / (1.f + expf(-s.w));
      *reinterpret_cast<float4*>(sigs + (size_t)b * HW +
                                 pblk * 256 + threadIdx.x * 4) = s;
    }
  }
}

// ---------------------------------------------------------------------------
// phigather (byte-identical to the 118.6us R5 config: 4 px/thread, 8 ch/blk,
// 1024 blocks = 4 waves/SIMD; 512-block variants regressed).
// Window trick: all x-dependent neighbor reads use an 8-wide window
// [x0-2 .. x0+5]: L=float2@max(x0-2,0), C=float4@x0, R=float2@min(x0+4,W-2);
// value(kx, px j) = a[j+2*kx]. Out-of-range taps have phi==0 (zero-pad),
// so clamped window entries may hold garbage safely.
// ---------------------------------------------------------------------------
__global__ __launch_bounds__(256) void phigather_kernel(
    const float* __restrict__ inp, const float* __restrict__ rimg,
    const float* __restrict__ sigs, const float* __restrict__ Mt,
    const float* __restrict__ GXX, const float* __restrict__ GYY,
    const float* __restrict__ G, float* __restrict__ out)
{
  const int cg = blockIdx.x;                             // 0..7, 8 channels
  const int p0 = (blockIdx.y * 256 + threadIdx.x) * 4;   // 4 px per thread
  const int b = blockIdx.z;
  const int x0 = p0 & (W - 1);
  const int y  = p0 >> 8;

  const int xl = max(x0 - 2, 0);          // 8B-aligned
  const int xr = min(x0 + 4, W - 2);      // 8B-aligned

  int rowoff[3];
  bool vrow[3];
#pragma unroll
  for (int ky = 0; ky < 3; ky++) {
    const int cy = y + 2 * (ky - 1);
    vrow[ky] = ((unsigned)cy < (unsigned)H);
    rowoff[ky] = min(max(cy, 0), H - 1) * W;
  }

  const float* rb = rimg + (size_t)b * 3 * HW;
  const float* sb = sigs + (size_t)b * HW;

  // t = G^T r per pixel (float4 lanes = the 4 pixels)
  const float4 r0 = *reinterpret_cast<const float4*>(rb + p0);
  const float4 r1 = *reinterpret_cast<const float4*>(rb + HW + p0);
  const float4 r2 = *reinterpret_cast<const float4*>(rb + 2 * HW + p0);
  float4 t0, t1, t2;
  {
    const float g0 = G[0], g1 = G[1], g2 = G[2];
    const float g3 = G[3], g4 = G[4], g5 = G[5];
    const float g6 = G[6], g7 = G[7], g8 = G[8];
    t0.x = r0.x * g0 + r1.x * g3 + r2.x * g6;
    t0.y = r0.y * g0 + r1.y * g3 + r2.y * g6;
    t0.z = r0.z * g0 + r1.z * g3 + r2.z * g6;
    t0.w = r0.w * g0 + r1.w * g3 + r2.w * g6;
    t1.x = r0.x * g1 + r1.x * g4 + r2.x * g7;
    t1.y = r0.y * g1 + r1.y * g4 + r2.y * g7;
    t1.z = r0.z * g1 + r1.z * g4 + r2.z * g7;
    t1.w = r0.w * g1 + r1.w * g4 + r2.w * g7;
    t2.x = r0.x * g2 + r1.x * g5 + r2.x * g8;
    t2.y = r0.y * g2 + r1.y * g5 + r2.y * g8;
    t2.z = r0.z * g2 + r1.z * g5 + r2.z * g8;
    t2.w = r0.w * g2 + r1.w * g5 + r2.w * g8;
  }

  // Mt row-y window (shared by all ky)
  float mrow[8];
  {
    const float2 L = *reinterpret_cast<const float2*>(Mt + y * W + xl);
    const float4 C = *reinterpret_cast<const float4*>(Mt + y * W + x0);
    const float2 R = *reinterpret_cast<const float2*>(Mt + y * W + xr);
    mrow[0] = L.x; mrow[1] = L.y; mrow[2] = C.x; mrow[3] = C.y;
    mrow[4] = C.z; mrow[5] = C.w; mrow[6] = R.x; mrow[7] = R.y;
  }
  // GXX[kx][x0..x0+3] (aligned)
  float4 gxxv[3];
#pragma unroll
  for (int kx = 0; kx < 3; kx++)
    gxxv[kx] = *reinterpret_cast<const float4*>(GXX + kx * 256 + x0);

  float4 ph[9];
#pragma unroll
  for (int ky = 0; ky < 3; ky++) {
    const int ro = rowoff[ky];
    float a0[8], a1[8], a2[8], as_[8];
    {
      const float2 L0 = *reinterpret_cast<const float2*>(rb + ro + xl);
      const float4 C0 = *reinterpret_cast<const float4*>(rb + ro + x0);
      const float2 R0 = *reinterpret_cast<const float2*>(rb + ro + xr);
      a0[0]=L0.x; a0[1]=L0.y; a0[2]=C0.x; a0[3]=C0.y;
      a0[4]=C0.z; a0[5]=C0.w; a0[6]=R0.x; a0[7]=R0.y;
      const float2 L1 = *reinterpret_cast<const float2*>(rb + HW + ro + xl);
      const float4 C1 = *reinterpret_cast<const float4*>(rb + HW + ro + x0);
      const float2 R1 = *reinterpret_cast<const float2*>(rb + HW + ro + xr);
      a1[0]=L1.x; a1[1]=L1.y; a1[2]=C1.x; a1[3]=C1.y;
      a1[4]=C1.z; a1[5]=C1.w; a1[6]=R1.x; a1[7]=R1.y;
      const float2 L2 = *reinterpret_cast<const float2*>(rb + 2 * HW + ro + xl);
      const float4 C2 = *reinterpret_cast<const float4*>(rb + 2 * HW + ro + x0);
      const float2 R2 = *reinterpret_cast<const float2*>(rb + 2 * HW + ro + xr);
      a2[0]=L2.x; a2[1]=L2.y; a2[2]=C2.x; a2[3]=C2.y;
      a2[4]=C2.z; a2[5]=C2.w; a2[6]=R2.x; a2[7]=R2.y;
      const float2 Ls = *reinterpret_cast<const float2*>(sb + ro + xl);
      const float4 Cs = *reinterpret_cast<const float4*>(sb + ro + x0);
      const float2 Rs = *reinterpret_cast<const float2*>(sb + ro + xr);
      as_[0]=Ls.x; as_[1]=Ls.y; as_[2]=Cs.x; as_[3]=Cs.y;
      as_[4]=Cs.z; as_[5]=Cs.w; as_[6]=Rs.x; as_[7]=Rs.y;
    }
    const float4 mc = *reinterpret_cast<const float4*>(Mt + ro + x0);
    const float gyy = GYY[ky * 256 + y];

#pragma unroll
    for (int kx = 0; kx < 3; kx++) {
      float4 p;
      {
        const int rel = 0 + 2 * kx;
        const float fs = t0.x * a0[rel] + t1.x * a1[rel] + t2.x * a2[rel]
                       + gxxv[kx].x + gyy + mrow[rel] + mc.x;
        const bool v = vrow[ky] && ((unsigned)(x0 + 0 + 2 * (kx - 1)) < (unsigned)W);
        p.x = v ? as_[rel] * fs : 0.f;
      }
      {
        const int rel = 1 + 2 * kx;
        const float fs = t0.y * a0[rel] + t1.y * a1[rel] + t2.y * a2[rel]
                       + gxxv[kx].y + gyy + mrow[rel] + mc.y;
        const bool v = vrow[ky] && ((unsigned)(x0 + 1 + 2 * (kx - 1)) < (unsigned)W);
        p.y = v ? as_[rel] * fs : 0.f;
      }
      {
        const int rel = 2 + 2 * kx;
        const float fs = t0.z * a0[rel] + t1.z * a1[rel] + t2.z * a2[rel]
                       + gxxv[kx].z + gyy + mrow[rel] + mc.z;
        const bool v = vrow[ky] && ((unsigned)(x0 + 2 + 2 * (kx - 1)) < (unsigned)W);
        p.z = v ? as_[rel] * fs : 0.f;
      }
      {
        const int rel = 3 + 2 * kx;
        const float fs = t0.w * a0[rel] + t1.w * a1[rel] + t2.w * a2[rel]
                       + gxxv[kx].w + gyy + mrow[rel] + mc.w;
        const bool v = vrow[ky] && ((unsigned)(x0 + 3 + 2 * (kx - 1)) < (unsigned)W);
        p.w = v ? as_[rel] * fs : 0.f;
      }
      ph[ky * 3 + kx] = p;
    }
  }

  // phase 2: 8 channels, float4 in/out
  const float* ib = inp + ((size_t)b * CF + cg * 8) * HW;
  float* ob = out + ((size_t)b * CF + cg * 8) * HW + p0;
#pragma unroll 4
  for (int c = 0; c < 8; c++) {
    const float* ic = ib + (size_t)c * HW;
    float4 acc = {0.f, 0.f, 0.f, 0.f};
#pragma unroll
    for (int ky = 0; ky < 3; ky++) {
      const int ro = rowoff[ky];
      const float2 L = *reinterpret_cast<const float2*>(ic + ro + xl);
      const float4 C = *reinterpret_cast<const float4*>(ic + ro + x0);
      const float2 R = *reinterpret_cast<const float2*>(ic + ro + xr);
      const float a[8] = {L.x, L.y, C.x, C.y, C.z, C.w, R.x, R.y};
#pragma unroll
      for (int kx = 0; kx < 3; kx++) {
        const float4 w = ph[ky * 3 + kx];
        acc.x += w.x * a[0 + 2 * kx];
        acc.y += w.y * a[1 + 2 * kx];
        acc.z += w.z * a[2 + 2 * kx];
        acc.w += w.w * a[3 + 2 * kx];
      }
    }
    *reinterpret_cast<float4*>(ob + (size_t)c * HW) = acc;
  }
}

// ---------------------------------------------------------------------------
extern "C" void kernel_launch(void* const* d_in, const int* in_sizes, int n_in,
                              void* d_out, int out_size, void* d_ws, size_t ws_size,
                              hipStream_t stream)
{
  const float* inp    = (const float*)d_in[0];
  const float* img    = (const float*)d_in[1];
  const float* w_pos  = (const float*)d_in[2];
  const float* w_img  = (const float*)d_in[3];
  const float* w_comp = (const float*)d_in[4];
  float* out = (float*)d_out;
  float* ws  = (float*)d_ws;

  float* Mt   = ws + OFF_MT;
  float* GXX  = ws + OFF_GXX;
  float* GYY  = ws + OFF_GYY;
  float* G    = ws + OFF_G;
  float* rimg = ws + OFF_RIMG;
  float* sigs = ws + OFF_S;

  hipLaunchKernelGGL(prep_kernel, dim3(PREP_BLOCKS), dim3(256), 0, stream,
                     img, inp, w_comp, w_img, w_pos,
                     rimg, sigs, Mt, GXX, GYY, G);

  hipLaunchKernelGGL(phigather_kernel, dim3(8, HW / 1024, Bn), dim3(256), 0, stream,
                     inp, rimg, sigs, Mt, GXX, GYY, G, out);
}

// Round 7
// 117.176 us; speedup vs baseline: 2.2416x; 2.2416x over previous
//
#include <hip/hip_runtime.h>
#include <math.h>

namespace {
constexpr int Bn = 2, CF = 64;
constexpr int H = 256, W = 256, HW = H * W;
constexpr int IH = 512, IW = 512;

// ws layout in floats
constexpr int OFF_MT   = 0;                        // Mt[y][x], 256*256
constexpr int OFF_GXX  = OFF_MT + 256 * 256;       // [3][256] j-major
constexpr int OFF_GYY  = OFF_GXX + 3 * 256;        // [3][256]
constexpr int OFF_G    = OFF_GYY + 3 * 256;        // 3x3 = w_img^T w_img (pad 16)
constexpr int OFF_RIMG = OFF_G + 16;               // [b][c3][HW]
constexpr int OFF_S    = OFF_RIMG + Bn * 3 * HW;   // sigs: Bn*HW = sigmoid(smap)
constexpr int OFF_PX   = OFF_S + Bn * HW;          // [32][256]
constexpr int OFF_PY   = OFF_PX + 32 * 256;        // [32][256]

// fused prep partition (rimg now 2 px/thread -> 768 blocks)
constexpr int GRAM_BLOCKS = 256;
constexpr int RIMG_BLOCKS = Bn * 3 * (HW / 512);   // 768
constexpr int SIGS_BLOCKS = Bn * (HW / 256);       // 512 (float4, 4 px/thread)
constexpr int PREP_BLOCKS = GRAM_BLOCKS + RIMG_BLOCKS + SIGS_BLOCKS; // 1536
}

// ---------------------------------------------------------------------------
// P1: PX[o][t], PY[o][t] sinusoid projections (32x256 transcendentals total).
// Kept as its own tiny kernel: folding gram's math into prep (R6) exploded
// VGPR/LDS for ALL prep branches -> 198us. Never again.
// ---------------------------------------------------------------------------
__global__ __launch_bounds__(256) void pxy_kernel(
    const float* __restrict__ w_pos,
    float* __restrict__ PX, float* __restrict__ PY)
{
  const int t = threadIdx.x;
  const int o = blockIdx.x;
  float s[16], c[16];
#pragma unroll
  for (int i = 0; i < 16; i++) {
    float d = expf((float)(2 * i) * (-0.2878231366242557f)); // -ln(1e4)/32
    float a = (float)t * d;
    s[i] = sinf(a);
    c[i] = cosf(a);
  }
  const float* wr = w_pos + o * 64;
  float ax = 0.f, ay = 0.f;
#pragma unroll
  for (int i = 0; i < 16; i++) {
    ax += wr[2 * i] * s[i] + wr[2 * i + 1] * c[i];
    ay += wr[32 + 2 * i] * s[i] + wr[33 + 2 * i] * c[i];
  }
  PX[o * 256 + t] = ax;
  PY[o * 256 + t] = ay;
}

// ---------------------------------------------------------------------------
// prep (fused, 1536 blocks):
//   [0,256)     gram: Mt[t][a] = dot_o(PX[:,a],PY[:,t]); blk 0 adds GXX/GYY/G.
//   [256,1024)  rimg: antialiased 2x downsample, 2 px/thread, 3 aligned
//               float4 window loads per row (edge mis-maps land on
//               zero-weight taps; see window comment below).
//   [1024,1536) sigs: sigmoid(dot_c(inp,w_comp)), float4 loads.
// All branches block-uniform; low VGPR/LDS in every branch.
// ---------------------------------------------------------------------------
__device__ __forceinline__ void resize_taps(int p, int n, float w[4], int idx[4])
{
#pragma unroll
  for (int r = 0; r < 4; r++) {
    int q = 2 * p - 1 + r;
    idx[r] = min(max(q, 0), 2 * n - 1);
  }
  if (p == 0)          { w[0] = 0.f;        w[1] = 3.f / 7.f; w[2] = 3.f / 7.f; w[3] = 1.f / 7.f; }
  else if (p == n - 1) { w[0] = 1.f / 7.f;  w[1] = 3.f / 7.f; w[2] = 3.f / 7.f; w[3] = 0.f; }
  else                 { w[0] = 0.125f;     w[1] = 0.375f;    w[2] = 0.375f;    w[3] = 0.125f; }
}

__global__ __launch_bounds__(256) void prep_kernel(
    const float* __restrict__ img, const float* __restrict__ inp,
    const float* __restrict__ w_comp, const float* __restrict__ w_img,
    const float* __restrict__ PX, const float* __restrict__ PY,
    float* __restrict__ rimg, float* __restrict__ sigs,
    float* __restrict__ Mt, float* __restrict__ GXX, float* __restrict__ GYY,
    float* __restrict__ G)
{
  __shared__ float4 red4[256];
  const int gid = blockIdx.x;

  if (gid < GRAM_BLOCKS) {
    // ---- gram part ----
    const int a = threadIdx.x;
    const int t = gid;

    float m = 0.f;
#pragma unroll
    for (int o = 0; o < 32; o++) m += PX[o * 256 + a] * PY[o * 256 + t];
    Mt[t * 256 + a] = m;

    if (t == 0) {
#pragma unroll
      for (int j = 0; j < 3; j++) {
        const int nb = a + 2 * (j - 1);
        float gx = 0.f, gy = 0.f;
        if (nb >= 0 && nb < 256) {
#pragma unroll
          for (int o = 0; o < 32; o++) {
            gx += PX[o * 256 + a] * PX[o * 256 + nb];
            gy += PY[o * 256 + a] * PY[o * 256 + nb];
          }
        }
        GXX[j * 256 + a] = gx;
        GYY[j * 256 + a] = gy;
      }
      if (a < 9) {
        const int i = a / 3, j = a % 3;
        float g = 0.f;
#pragma unroll
        for (int o = 0; o < 32; o++) g += w_img[o * 3 + i] * w_img[o * 3 + j];
        G[a] = g;
      }
    }
  } else if (gid < GRAM_BLOCKS + RIMG_BLOCKS) {
    // ---- rimg part: 2 adjacent output px per thread ----
    // Input cols needed for outputs (x0, x0+1), x0 even: 2x0-1 .. 2x0+4.
    // Three aligned float4 blocks: B0@max(2x0-4,0), B1@2x0, B2@min(2x0+4,IW-4)
    // cover them; a[i] = col (2x0-4)+i, tap q -> rel q-2x0+4 in [3,8].
    // Edge mis-maps (x0=0 left, x0=254 right) only hit taps whose resize
    // weight is exactly 0, so garbage there is harmless.
    const int rid = gid - GRAM_BLOCKS;
    const int b = rid / 384;
    const int rem = rid % 384;
    const int c = rem / 128;
    const int pp = (rem % 128) * 512 + threadIdx.x * 2;  // even pixel index
    const int x0 = pp & (W - 1);                          // even
    const int y = pp >> 8;

    float wy[4], wxa[4], wxb[4];
    int ry[4], duma[4], dumb[4];
    resize_taps(y, H, wy, ry);
    resize_taps(x0, W, wxa, duma);
    resize_taps(x0 + 1, W, wxb, dumb);

    const int c0 = max(2 * x0 - 4, 0);
    const int c1 = 2 * x0;
    const int c2 = min(2 * x0 + 4, IW - 4);

    const float* ip = img + ((size_t)(b * 3 + c) * IH) * IW;
    float acc0 = 0.f, acc1 = 0.f;
#pragma unroll
    for (int r = 0; r < 4; r++) {
      const float* rowp = ip + ry[r] * IW;
      const float4 q0 = *reinterpret_cast<const float4*>(rowp + c0);
      const float4 q1 = *reinterpret_cast<const float4*>(rowp + c1);
      const float4 q2 = *reinterpret_cast<const float4*>(rowp + c2);
      const float a[12] = {q0.x, q0.y, q0.z, q0.w,
                           q1.x, q1.y, q1.z, q1.w,
                           q2.x, q2.y, q2.z, q2.w};
      const float s0 = wxa[0] * a[3] + wxa[1] * a[4] + wxa[2] * a[5] + wxa[3] * a[6];
      const float s1 = wxb[0] * a[5] + wxb[1] * a[6] + wxb[2] * a[7] + wxb[3] * a[8];
      acc0 += wy[r] * s0;
      acc1 += wy[r] * s1;
    }
    float2 o2; o2.x = acc0; o2.y = acc1;
    *reinterpret_cast<float2*>(rimg + ((size_t)(b * 3 + c)) * HW + pp) = o2;
  } else {
    // ---- sigs part: float4, 4 px/thread, LDS float4 reduce ----
    const int sid = gid - (GRAM_BLOCKS + RIMG_BLOCKS);
    const int b = sid / (HW / 256);
    const int pblk = sid % (HW / 256);
    const int lane = threadIdx.x & 63;
    const int cg = threadIdx.x >> 6;         // 0..3
    const int p0 = pblk * 256 + lane * 4;

    const float* ib = inp + (size_t)b * CF * HW + (size_t)cg * 16 * HW + p0;
    float4 acc = {0.f, 0.f, 0.f, 0.f};
#pragma unroll
    for (int c = 0; c < 16; c++) {
      const float4 v = *reinterpret_cast<const float4*>(ib + (size_t)c * HW);
      const float wc = w_comp[cg * 16 + c];
      acc.x += v.x * wc; acc.y += v.y * wc;
      acc.z += v.z * wc; acc.w += v.w * wc;
    }
    red4[threadIdx.x] = acc;
    __syncthreads();
    if (threadIdx.x < 64) {
      const float4 a = red4[threadIdx.x];
      const float4 b1 = red4[threadIdx.x + 64];
      const float4 c1 = red4[threadIdx.x + 128];
      const float4 d = red4[threadIdx.x + 192];
      float4 s;
      s.x = (a.x + b1.x) + (c1.x + d.x);
      s.y = (a.y + b1.y) + (c1.y + d.y);
      s.z = (a.z + b1.z) + (c1.z + d.z);
      s.w = (a.w + b1.w) + (c1.w + d.w);
      s.x = 1.f / (1.f + expf(-s.x));
      s.y = 1.f / (1.f + expf(-s.y));
      s.z = 1.f / (1.f + expf(-s.z));
      s.w = 1.f / (1.f + expf(-s.w));
      *reinterpret_cast<float4*>(sigs + (size_t)b * HW +
                                 pblk * 256 + threadIdx.x * 4) = s;
    }
  }
}

// ---------------------------------------------------------------------------
// phigather (byte-identical to the 118.6us R5 config: 4 px/thread, 8 ch/blk,
// 1024 blocks = 4 waves/SIMD; 512-block variants regressed).
// Window trick: all x-dependent neighbor reads use an 8-wide window
// [x0-2 .. x0+5]: L=float2@max(x0-2,0), C=float4@x0, R=float2@min(x0+4,W-2);
// value(kx, px j) = a[j+2*kx]. Out-of-range taps have phi==0 (zero-pad),
// so clamped window entries may hold garbage safely.
// ---------------------------------------------------------------------------
__global__ __launch_bounds__(256) void phigather_kernel(
    const float* __restrict__ inp, const float* __restrict__ rimg,
    const float* __restrict__ sigs, const float* __restrict__ Mt,
    const float* __restrict__ GXX, const float* __restrict__ GYY,
    const float* __restrict__ G, float* __restrict__ out)
{
  const int cg = blockIdx.x;                             // 0..7, 8 channels
  const int p0 = (blockIdx.y * 256 + threadIdx.x) * 4;   // 4 px per thread
  const int b = blockIdx.z;
  const int x0 = p0 & (W - 1);
  const int y  = p0 >> 8;

  const int xl = max(x0 - 2, 0);          // 8B-aligned
  const int xr = min(x0 + 4, W - 2);      // 8B-aligned

  int rowoff[3];
  bool vrow[3];
#pragma unroll
  for (int ky = 0; ky < 3; ky++) {
    const int cy = y + 2 * (ky - 1);
    vrow[ky] = ((unsigned)cy < (unsigned)H);
    rowoff[ky] = min(max(cy, 0), H - 1) * W;
  }

  const float* rb = rimg + (size_t)b * 3 * HW;
  const float* sb = sigs + (size_t)b * HW;

  // t = G^T r per pixel (float4 lanes = the 4 pixels)
  const float4 r0 = *reinterpret_cast<const float4*>(rb + p0);
  const float4 r1 = *reinterpret_cast<const float4*>(rb + HW + p0);
  const float4 r2 = *reinterpret_cast<const float4*>(rb + 2 * HW + p0);
  float4 t0, t1, t2;
  {
    const float g0 = G[0], g1 = G[1], g2 = G[2];
    const float g3 = G[3], g4 = G[4], g5 = G[5];
    const float g6 = G[6], g7 = G[7], g8 = G[8];
    t0.x = r0.x * g0 + r1.x * g3 + r2.x * g6;
    t0.y = r0.y * g0 + r1.y * g3 + r2.y * g6;
    t0.z = r0.z * g0 + r1.z * g3 + r2.z * g6;
    t0.w = r0.w * g0 + r1.w * g3 + r2.w * g6;
    t1.x = r0.x * g1 + r1.x * g4 + r2.x * g7;
    t1.y = r0.y * g1 + r1.y * g4 + r2.y * g7;
    t1.z = r0.z * g1 + r1.z * g4 + r2.z * g7;
    t1.w = r0.w * g1 + r1.w * g4 + r2.w * g7;
    t2.x = r0.x * g2 + r1.x * g5 + r2.x * g8;
    t2.y = r0.y * g2 + r1.y * g5 + r2.y * g8;
    t2.z = r0.z * g2 + r1.z * g5 + r2.z * g8;
    t2.w = r0.w * g2 + r1.w * g5 + r2.w * g8;
  }

  // Mt row-y window (shared by all ky)
  float mrow[8];
  {
    const float2 L = *reinterpret_cast<const float2*>(Mt + y * W + xl);
    const float4 C = *reinterpret_cast<const float4*>(Mt + y * W + x0);
    const float2 R = *reinterpret_cast<const float2*>(Mt + y * W + xr);
    mrow[0] = L.x; mrow[1] = L.y; mrow[2] = C.x; mrow[3] = C.y;
    mrow[4] = C.z; mrow[5] = C.w; mrow[6] = R.x; mrow[7] = R.y;
  }
  // GXX[kx][x0..x0+3] (aligned)
  float4 gxxv[3];
#pragma unroll
  for (int kx = 0; kx < 3; kx++)
    gxxv[kx] = *reinterpret_cast<const float4*>(GXX + kx * 256 + x0);

  float4 ph[9];
#pragma unroll
  for (int ky = 0; ky < 3; ky++) {
    const int ro = rowoff[ky];
    float a0[8], a1[8], a2[8], as_[8];
    {
      const float2 L0 = *reinterpret_cast<const float2*>(rb + ro + xl);
      const float4 C0 = *reinterpret_cast<const float4*>(rb + ro + x0);
      const float2 R0 = *reinterpret_cast<const float2*>(rb + ro + xr);
      a0[0]=L0.x; a0[1]=L0.y; a0[2]=C0.x; a0[3]=C0.y;
      a0[4]=C0.z; a0[5]=C0.w; a0[6]=R0.x; a0[7]=R0.y;
      const float2 L1 = *reinterpret_cast<const float2*>(rb + HW + ro + xl);
      const float4 C1 = *reinterpret_cast<const float4*>(rb + HW + ro + x0);
      const float2 R1 = *reinterpret_cast<const float2*>(rb + HW + ro + xr);
      a1[0]=L1.x; a1[1]=L1.y; a1[2]=C1.x; a1[3]=C1.y;
      a1[4]=C1.z; a1[5]=C1.w; a1[6]=R1.x; a1[7]=R1.y;
      const float2 L2 = *reinterpret_cast<const float2*>(rb + 2 * HW + ro + xl);
      const float4 C2 = *reinterpret_cast<const float4*>(rb + 2 * HW + ro + x0);
      const float2 R2 = *reinterpret_cast<const float2*>(rb + 2 * HW + ro + xr);
      a2[0]=L2.x; a2[1]=L2.y; a2[2]=C2.x; a2[3]=C2.y;
      a2[4]=C2.z; a2[5]=C2.w; a2[6]=R2.x; a2[7]=R2.y;
      const float2 Ls = *reinterpret_cast<const float2*>(sb + ro + xl);
      const float4 Cs = *reinterpret_cast<const float4*>(sb + ro + x0);
      const float2 Rs = *reinterpret_cast<const float2*>(sb + ro + xr);
      as_[0]=Ls.x; as_[1]=Ls.y; as_[2]=Cs.x; as_[3]=Cs.y;
      as_[4]=Cs.z; as_[5]=Cs.w; as_[6]=Rs.x; as_[7]=Rs.y;
    }
    const float4 mc = *reinterpret_cast<const float4*>(Mt + ro + x0);
    const float gyy = GYY[ky * 256 + y];

#pragma unroll
    for (int kx = 0; kx < 3; kx++) {
      float4 p;
      {
        const int rel = 0 + 2 * kx;
        const float fs = t0.x * a0[rel] + t1.x * a1[rel] + t2.x * a2[rel]
                       + gxxv[kx].x + gyy + mrow[rel] + mc.x;
        const bool v = vrow[ky] && ((unsigned)(x0 + 0 + 2 * (kx - 1)) < (unsigned)W);
        p.x = v ? as_[rel] * fs : 0.f;
      }
      {
        const int rel = 1 + 2 * kx;
        const float fs = t0.y * a0[rel] + t1.y * a1[rel] + t2.y * a2[rel]
                       + gxxv[kx].y + gyy + mrow[rel] + mc.y;
        const bool v = vrow[ky] && ((unsigned)(x0 + 1 + 2 * (kx - 1)) < (unsigned)W);
        p.y = v ? as_[rel] * fs : 0.f;
      }
      {
        const int rel = 2 + 2 * kx;
        const float fs = t0.z * a0[rel] + t1.z * a1[rel] + t2.z * a2[rel]
                       + gxxv[kx].z + gyy + mrow[rel] + mc.z;
        const bool v = vrow[ky] && ((unsigned)(x0 + 2 + 2 * (kx - 1)) < (unsigned)W);
        p.z = v ? as_[rel] * fs : 0.f;
      }
      {
        const int rel = 3 + 2 * kx;
        const float fs = t0.w * a0[rel] + t1.w * a1[rel] + t2.w * a2[rel]
                       + gxxv[kx].w + gyy + mrow[rel] + mc.w;
        const bool v = vrow[ky] && ((unsigned)(x0 + 3 + 2 * (kx - 1)) < (unsigned)W);
        p.w = v ? as_[rel] * fs : 0.f;
      }
      ph[ky * 3 + kx] = p;
    }
  }

  // phase 2: 8 channels, float4 in/out
  const float* ib = inp + ((size_t)b * CF + cg * 8) * HW;
  float* ob = out + ((size_t)b * CF + cg * 8) * HW + p0;
#pragma unroll 4
  for (int c = 0; c < 8; c++) {
    const float* ic = ib + (size_t)c * HW;
    float4 acc = {0.f, 0.f, 0.f, 0.f};
#pragma unroll
    for (int ky = 0; ky < 3; ky++) {
      const int ro = rowoff[ky];
      const float2 L = *reinterpret_cast<const float2*>(ic + ro + xl);
      const float4 C = *reinterpret_cast<const float4*>(ic + ro + x0);
      const float2 R = *reinterpret_cast<const float2*>(ic + ro + xr);
      const float a[8] = {L.x, L.y, C.x, C.y, C.z, C.w, R.x, R.y};
#pragma unroll
      for (int kx = 0; kx < 3; kx++) {
        const float4 w = ph[ky * 3 + kx];
        acc.x += w.x * a[0 + 2 * kx];
        acc.y += w.y * a[1 + 2 * kx];
        acc.z += w.z * a[2 + 2 * kx];
        acc.w += w.w * a[3 + 2 * kx];
      }
    }
    *reinterpret_cast<float4*>(ob + (size_t)c * HW) = acc;
  }
}

// ---------------------------------------------------------------------------
extern "C" void kernel_launch(void* const* d_in, const int* in_sizes, int n_in,
                              void* d_out, int out_size, void* d_ws, size_t ws_size,
                              hipStream_t stream)
{
  const float* inp    = (const float*)d_in[0];
  const float* img    = (const float*)d_in[1];
  const float* w_pos  = (const float*)d_in[2];
  const float* w_img  = (const float*)d_in[3];
  const float* w_comp = (const float*)d_in[4];
  float* out = (float*)d_out;
  float* ws  = (float*)d_ws;

  float* Mt   = ws + OFF_MT;
  float* GXX  = ws + OFF_GXX;
  float* GYY  = ws + OFF_GYY;
  float* G    = ws + OFF_G;
  float* rimg = ws + OFF_RIMG;
  float* sigs = ws + OFF_S;
  float* PX   = ws + OFF_PX;
  float* PY   = ws + OFF_PY;

  hipLaunchKernelGGL(pxy_kernel, dim3(32), dim3(256), 0, stream, w_pos, PX, PY);

  hipLaunchKernelGGL(prep_kernel, dim3(PREP_BLOCKS), dim3(256), 0, stream,
                     img, inp, w_comp, w_img, PX, PY,
                     rimg, sigs, Mt, GXX, GYY, G);

  hipLaunchKernelGGL(phigather_kernel, dim3(8, HW / 1024, Bn), dim3(256), 0, stream,
                     inp, rimg, sigs, Mt, GXX, GYY, G, out);
}